// Round 1
// 430.397 us; speedup vs baseline: 1.0843x; 1.0843x over previous
//
#include <hip/hip_runtime.h>
#include <stdint.h>

// Problem constants
#define B 2048
#define S 201
#define HALF 100                 // S/2
#define D 128
#define BS (B * S)               // 411648
#define OFF_POS (BS * D)         // 52690944  : pos_enc starts here (floats)
#define OFF_VT  (2 * OFF_POS)    // 105381888 : visited_time (floats)
#define OFF_T2  (OFF_VT + BS)    // 105793536 : top2 (floats, 2 per bs)
#define F4B (S * (D / 4))        // 6432      : float4 elements per batch in [B,S,D]
#define TPB 256

typedef float vf4 __attribute__((ext_vector_type(4)));
typedef float vf2 __attribute__((ext_vector_type(2)));

// One block = one batch. Wave 0 stages sol + lane 0 runs the (serial) chase,
// divergence-free; waves 1-3 stream this batch's x_embedding concurrently
// (no vt dependency). After __syncthreads, all 256 threads write this batch's
// pos_enc from LDS vis[] + L2-resident pattern, plus vt/top2 dumps.
// LDS/block ~1 KB (was 64 KB for ALL blocks -> 2 blocks/CU cap).
__global__ __launch_bounds__(TPB, 4) void fused(const float* __restrict__ x,
                                                const int* __restrict__ sol,
                                                const float* __restrict__ W,
                                                const float* __restrict__ pattern,
                                                float* __restrict__ out) {
    __shared__ uint8_t  s_sol[S];
    __shared__ uint8_t  s_vis[S];
    __shared__ uint8_t  s_nx[HALF + 1];
    __shared__ uint8_t  s_pv[HALF + 1];
    __shared__ uint16_t s_t2[S];

    const int tid = threadIdx.x;
    const int b   = blockIdx.x;

    if (tid < 64) {
        // stage sol (coalesced) + zero vis/t2 — all wave-0, ordered by waitcnt
        for (int j = tid; j < S; j += 64) {
            s_sol[j] = (uint8_t)sol[b * S + j];
            s_vis[j] = 0;
            s_t2[j]  = 0;
        }
        // wave-0 DS writes complete before lane 0's reads (same-wave, in-order DS)
        asm volatile("s_waitcnt lgkmcnt(0)" ::: "memory");

        if (tid == 0) {
            int pre = 0;
            int head = 0, second = 1;  // head==0 -> second==1; 1 open -> second==0
            unsigned long long m0 = 0, m1 = 0;  // in-list bitmask, pickups 1..100

            for (int i = 0; i < S; ++i) {
                int cur = s_sol[pre];
                s_vis[cur] = (uint8_t)(i + 1);
                if (cur != 0) {
                    if (cur <= HALF) {
                        // push: new element is the new maximum (time i+1)
                        s_nx[cur]  = (uint8_t)head;
                        s_pv[head] = (uint8_t)cur;   // pv[0] harmless
                        second = head;
                        head   = cur;
                        if (cur < 64) m0 |= 1ull << cur; else m1 |= 1ull << (cur - 64);
                    } else {
                        int q = cur - HALF;          // 1..100
                        bool in = (q < 64) ? ((m0 >> q) & 1ull)
                                           : ((m1 >> (q - 64)) & 1ull);
                        if (in) {
                            if (q < 64) m0 &= ~(1ull << q); else m1 &= ~(1ull << (q - 64));
                            if (q == head) {
                                head = second;
                                second = (head == 0) ? 1 : (int)s_nx[head];
                            } else if (q == second) {
                                int n2 = s_nx[q];
                                s_nx[head] = (uint8_t)n2;
                                s_pv[n2]   = (uint8_t)head;
                                second = n2;
                            } else {
                                int p = s_pv[q], n2 = s_nx[q];
                                s_nx[p]  = (uint8_t)n2;
                                s_pv[n2] = (uint8_t)p;
                            }
                        }
                    }
                }
                s_t2[cur] = (uint16_t)(head | (second << 8));
                pre = cur;
            }
        }
    } else {
        // waves 1-3: x_embedding for batch b (6432 float4, coalesced NT stores)
        const int t  = tid - 64;          // 0..191, multiple-of-32 stride below
        const int d4 = t & 31;
        const float4* W4 = (const float4*)W;
        float4 w0 = W4[d4 * 2];           // {W[4d4][0],W[4d4][1],W[4d4+1][0],W[4d4+1][1]}
        float4 w1 = W4[d4 * 2 + 1];
        const float2* x2 = (const float2*)x + b * S;   // this batch's x, L1-hot
        vf4* o4 = (vf4*)out + b * F4B;
        for (int idx4 = t; idx4 < F4B; idx4 += 192) {
            float2 xv = x2[idx4 >> 5];
            vf4 o;
            o.x = xv.x * w0.x + xv.y * w0.y;
            o.y = xv.x * w0.z + xv.y * w0.w;
            o.z = xv.x * w1.x + xv.y * w1.y;
            o.w = xv.x * w1.z + xv.y * w1.w;
            __builtin_nontemporal_store(o, &o4[idx4]);
        }
    }
    __syncthreads();

    // phase 2: pos_enc for batch b (pattern is 103 KB, L2-resident) + dumps
    {
        const vf4* p4 = (const vf4*)pattern;
        vf4* o4 = (vf4*)(out + OFF_POS) + b * F4B;
        for (int idx4 = tid; idx4 < F4B; idx4 += TPB) {
            int vt  = s_vis[idx4 >> 5];            // 1..201 (broadcast read)
            int row = (vt >= S) ? (vt - S) : vt;   // vt % S
            vf4 v = p4[row * 32 + (idx4 & 31)];
            __builtin_nontemporal_store(v, &o4[idx4]);
        }
        for (int j = tid; j < S; j += TPB) {
            out[OFF_VT + b * S + j] = (float)s_vis[j];
            int tt = s_t2[j];
            vf2 f2 = { (float)(tt & 255), (float)(tt >> 8) };
            __builtin_nontemporal_store(f2, ((vf2*)(out + OFF_T2)) + b * S + j);
        }
    }
}

extern "C" void kernel_launch(void* const* d_in, const int* in_sizes, int n_in,
                              void* d_out, int out_size, void* d_ws, size_t ws_size,
                              hipStream_t stream) {
    const float* x       = (const float*)d_in[0];   // [2048,201,2] f32
    const int*   sol     = (const int*)d_in[1];     // [2048,201] int
    const float* W       = (const float*)d_in[2];   // [128,2] f32
    const float* pattern = (const float*)d_in[3];   // [201,128] f32
    float* out = (float*)d_out;

    hipLaunchKernelGGL(fused, dim3(B), dim3(TPB), 0, stream, x, sol, W, pattern, out);
}